// Round 1
// 212.345 us; speedup vs baseline: 1.1015x; 1.1015x over previous
//
#include <hip/hip_runtime.h>

typedef short bf16x8 __attribute__((ext_vector_type(8)));
typedef float f32x4 __attribute__((ext_vector_type(4)));

#define MFMA16(a,b,c) __builtin_amdgcn_mfma_f32_16x16x32_bf16((a),(b),(c),0,0,0)

static __device__ __forceinline__ unsigned short f2bf(float f){
  unsigned u; __builtin_memcpy(&u, &f, 4);
  u += 0x7fffu + ((u >> 16) & 1u);
  return (unsigned short)(u >> 16);
}
static __device__ __forceinline__ unsigned f32u(float f){
  unsigned u; __builtin_memcpy(&u, &f, 4); return u;
}

// async global->LDS DMA, 16 B per lane; LDS dest = wave-uniform base + lane*16
static __device__ __forceinline__ void gload_lds16(const void* g, void* l) {
  __builtin_amdgcn_global_load_lds(
      (__attribute__((address_space(1))) void*)g,
      (__attribute__((address_space(3))) void*)l, 16, 0, 0);
}

// ---------------------------------------------------------------------------
// LDS XOR swizzle (T2): LDS[row][col ^ ((row&7)*8)] holds global[row][col]
// (cols in shorts, i.e. 16-byte chunk swap). global_load_lds writes LINEAR
// LDS, so the swizzle is applied by permuting the per-lane GLOBAL source
// column (rule #21: linear dest + inverse-swz source + swz on read).
// ---------------------------------------------------------------------------

// ---------------------------------------------------------------------------
// Stage f32 tensor -> bf16.
// ---------------------------------------------------------------------------
__global__ __launch_bounds__(256) void cvt_bf16(
    const float* __restrict__ in, unsigned short* __restrict__ out, int n) {
  int i = blockIdx.x * 256 + threadIdx.x;
  if (i < n) out[i] = f2bf(in[i]);
}

// ---------------------------------------------------------------------------
// T0: x [n][512 c][1024 p] f32 -> xT [n][1024 p][512 c] bf16
// ---------------------------------------------------------------------------
__global__ __launch_bounds__(256) void transpose_cvt(
    const float* __restrict__ in, unsigned short* __restrict__ out)
{
  __shared__ unsigned short tile[32][33];
  const long base = (long)blockIdx.z * 512 * 1024;
  const int t = threadIdx.x, tx = t & 31, ty = t >> 5;
  const int c0 = blockIdx.x * 32, r0 = blockIdx.y * 32;
  const float* ib = in + base;
#pragma unroll
  for (int i = 0; i < 4; ++i)
    tile[ty + i * 8][tx] = f2bf(ib[(long)(r0 + ty + i * 8) * 1024 + c0 + tx]);
  __syncthreads();
  unsigned short* ob = out + base;
#pragma unroll
  for (int i = 0; i < 4; ++i)
    ob[(long)(c0 + ty + i * 8) * 512 + r0 + tx] = tile[tx][ty + i * 8];
}

// ---------------------------------------------------------------------------
// K1: QKV GEMM (global_load_lds staging, XOR-swizzled LDS tiles).
// A = xT [n][1024 p][512 c] bf16, B = wq [1536 o][512 c] bf16, bias f32.
// Epilogue routes by o:
//   o in [0,512)    -> q_pd [n][h][p][64]  (qkv + 0)  PRE-SCALED by 0.125*log2e
//   o in [512,1024) -> k_pd [n][h][p][64]  (qkv + 8388608)
//   o in [1024,1536)-> v_cp [n][o-1024][p] (qkv + 16777216)
// ---------------------------------------------------------------------------
__global__ __launch_bounds__(256, 3) void gemm_qkv(
    const unsigned short* __restrict__ A, const unsigned short* __restrict__ B,
    unsigned short* __restrict__ qkvout, const float* __restrict__ bias)
{
  const int M = 1024, K = 512;
  __shared__ unsigned short As[128 * 64];   // 16 KB, linear DMA dest
  __shared__ unsigned short Bs[128 * 64];
  const int t = threadIdx.x, lane = t & 63, wv = t >> 6;
  const int quad = lane >> 4, ln = lane & 15;
  const int m0 = blockIdx.y * 128, n0 = blockIdx.x * 128;
  const long zb = blockIdx.z;
  A += zb * (long)M * K;

  // staging: lane -> linear LDS (row = wv*32+i*8+(lane>>3), chunk = lane&7);
  // source column pre-XOR'd so LDS holds the swizzled layout.
  const int srow = wv * 32 + (lane >> 3);
  const int scol = ((lane & 7) * 8) ^ ((lane >> 3) * 8);

  f32x4 zero = {0.f, 0.f, 0.f, 0.f};
  f32x4 acc[4][4];
#pragma unroll
  for (int i = 0; i < 4; ++i)
#pragma unroll
    for (int j = 0; j < 4; ++j) acc[i][j] = zero;

  const int wm = (wv & 1) * 64, wn = (wv >> 1) * 64;
  const int rsw = (ln & 7) * 8;   // read-side XOR (row&7 == ln&7)

  for (int kt = 0; kt < K; kt += 64) {
#pragma unroll
    for (int i = 0; i < 4; ++i) {
      gload_lds16(&A[(long)(m0 + srow + i * 8) * K + kt + scol],
                  &As[(wv * 32 + i * 8) * 64]);
      gload_lds16(&B[(long)(n0 + srow + i * 8) * K + kt + scol],
                  &Bs[(wv * 32 + i * 8) * 64]);
    }
    __syncthreads();   // drains vmcnt -> LDS data visible
#pragma unroll
    for (int kk = 0; kk < 64; kk += 32) {
      bf16x8 a[4], b[4];
#pragma unroll
      for (int i = 0; i < 4; ++i)
        a[i] = *(const bf16x8*)&As[(wm + i * 16 + ln) * 64 + ((kk + quad * 8) ^ rsw)];
#pragma unroll
      for (int j = 0; j < 4; ++j)
        b[j] = *(const bf16x8*)&Bs[(wn + j * 16 + ln) * 64 + ((kk + quad * 8) ^ rsw)];
#pragma unroll
      for (int i = 0; i < 4; ++i)
#pragma unroll
        for (int j = 0; j < 4; ++j)
          acc[i][j] = MFMA16(a[i], b[j], acc[i][j]);
    }
    __syncthreads();   // compute done before next overwrite
  }

#pragma unroll
  for (int j = 0; j < 4; ++j) {
    int o = n0 + wn + j * 16 + ln;
    float bb = bias[o];
    int part = o >> 9;          // 0=q, 1=k, 2=v
    int h = (o >> 6) & 7, d = o & 63;
    float qs = (part == 0) ? 0.18033688f : 1.0f;  // 0.125 * log2(e)
#pragma unroll
    for (int i = 0; i < 4; ++i) {
      int p = m0 + wm + i * 16 + quad * 4;
      f32x4 v = acc[i][j];
      if (part < 2) {
        unsigned short* dst = qkvout + (long)part * 8388608
            + ((long)(zb * 8 + h) * 1024 + p) * 64 + d;
#pragma unroll
        for (int r = 0; r < 4; ++r) dst[r * 64] = f2bf((v[r] + bb) * qs);
      } else {
        long cidx = ((long)zb * 512 + (o - 1024)) * 1024 + p;
        ushort4 st;
        st.x = f2bf(v[0] + bb); st.y = f2bf(v[1] + bb);
        st.z = f2bf(v[2] + bb); st.w = f2bf(v[3] + bb);
        *(ushort4*)&qkvout[16777216 + cidx] = st;
      }
    }
  }
}

// ---------------------------------------------------------------------------
// K3: OUT GEMM (same staging/swizzle) + bias + dropout-scale + residual; f32.
// ---------------------------------------------------------------------------
__global__ __launch_bounds__(256, 3) void gemm_out(
    const unsigned short* __restrict__ A, const unsigned short* __restrict__ B,
    float* __restrict__ C, const float* __restrict__ bias,
    const float* __restrict__ xin, const int* __restrict__ de_ptr)
{
  const int M = 1024, K = 512;
  __shared__ unsigned short As[128 * 64];
  __shared__ unsigned short Bs[128 * 64];
  const int t = threadIdx.x, lane = t & 63, wv = t >> 6;
  const int quad = lane >> 4, ln = lane & 15;
  const int m0 = blockIdx.y * 128, n0 = blockIdx.x * 128;
  const long zb = blockIdx.z;
  A += zb * (long)M * K;
  C += zb * 512l * M;
  xin += zb * 512l * M;

  const int srow = wv * 32 + (lane >> 3);
  const int scol = ((lane & 7) * 8) ^ ((lane >> 3) * 8);

  f32x4 zero = {0.f, 0.f, 0.f, 0.f};
  f32x4 acc[4][4];
#pragma unroll
  for (int i = 0; i < 4; ++i)
#pragma unroll
    for (int j = 0; j < 4; ++j) acc[i][j] = zero;

  const int wm = (wv & 1) * 64, wn = (wv >> 1) * 64;
  const int rsw = (ln & 7) * 8;

  for (int kt = 0; kt < K; kt += 64) {
#pragma unroll
    for (int i = 0; i < 4; ++i) {
      gload_lds16(&A[(long)(m0 + srow + i * 8) * K + kt + scol],
                  &As[(wv * 32 + i * 8) * 64]);
      gload_lds16(&B[(long)(n0 + srow + i * 8) * K + kt + scol],
                  &Bs[(wv * 32 + i * 8) * 64]);
    }
    __syncthreads();
#pragma unroll
    for (int kk = 0; kk < 64; kk += 32) {
      bf16x8 a[4], b[4];
#pragma unroll
      for (int i = 0; i < 4; ++i)
        a[i] = *(const bf16x8*)&As[(wm + i * 16 + ln) * 64 + ((kk + quad * 8) ^ rsw)];
#pragma unroll
      for (int j = 0; j < 4; ++j)
        b[j] = *(const bf16x8*)&Bs[(wn + j * 16 + ln) * 64 + ((kk + quad * 8) ^ rsw)];
#pragma unroll
      for (int i = 0; i < 4; ++i)
#pragma unroll
        for (int j = 0; j < 4; ++j)
          acc[i][j] = MFMA16(a[i], b[j], acc[i][j]);
    }
    __syncthreads();
  }

  float dscale = 1.0f / (1.0f - 0.1f * (float)de_ptr[0]);

#pragma unroll
  for (int j = 0; j < 4; ++j) {
    int o = n0 + wn + j * 16 + ln;
    float bb = bias[o];
#pragma unroll
    for (int i = 0; i < 4; ++i) {
      int p = m0 + wm + i * 16 + quad * 4;
      long cidx = (long)o * M + p;
      f32x4 v = acc[i][j];
      float4 rx = *(const float4*)&xin[cidx];
      float4 st;
      st.x = rx.x + (v[0] + bb) * dscale;
      st.y = rx.y + (v[1] + bb) * dscale;
      st.z = rx.z + (v[2] + bb) * dscale;
      st.w = rx.w + (v[3] + bb) * dscale;
      *(float4*)&C[cidx] = st;
    }
  }
}

// ---------------------------------------------------------------------------
// Flash attention v6: v5 + XOR-swizzled Ks/Vs (the 2.4e7 bank-conflict fix).
// K/V staged via global_load_lds into LINEAR LDS; the per-lane GLOBAL source
// column carries the inverse swizzle, fragment reads apply the same XOR.
// Ks[128x64] f(row)=((row&7)*8) shorts; Vs[64x128] same f; Ps stays padded.
// grid (8 q-tiles of 128 rows, 128 (n,h)); 4 waves; 2 Q-sets per wave.
// ---------------------------------------------------------------------------
__global__ __launch_bounds__(256, 3) void attn_kernel(
    const unsigned short* __restrict__ q_pd, const unsigned short* __restrict__ k_pd,
    const unsigned short* __restrict__ v_cp, unsigned short* __restrict__ y_pc)
{
  __shared__ unsigned short Ks[128 * 64];        // 16 KB, DMA dest
  __shared__ unsigned short Vs[64 * 128];        // 16 KB, DMA dest
  __shared__ unsigned short Ps[4 * 16 * 136];    // 17.4 KB, wave-private
  const int t = threadIdx.x, lane = t & 63, wv = t >> 6;
  const int quad = lane >> 4, ln = lane & 15;
  const int nh = blockIdx.y, n = nh >> 3, h = nh & 7;
  const int q0 = blockIdx.x * 128;

  // Q fragments for both sets (B-operand; n = ln, k = quad*8+j)
  bf16x8 qa[2][2];
#pragma unroll
  for (int s2 = 0; s2 < 2; ++s2) {
    const unsigned short* qb =
        q_pd + ((long)nh * 1024 + q0 + s2 * 64 + wv * 16 + ln) * 64;
    qa[s2][0] = *(const bf16x8*)(qb + quad * 8);
    qa[s2][1] = *(const bf16x8*)(qb + 32 + quad * 8);
  }

  f32x4 zero = {0.f, 0.f, 0.f, 0.f};
  float l_acc[2] = {0.f, 0.f};
  f32x4 o_acc[2][4];
#pragma unroll
  for (int s2 = 0; s2 < 2; ++s2)
#pragma unroll
    for (int nf = 0; nf < 4; ++nf) o_acc[s2][nf] = zero;

  const unsigned short* kg0 = k_pd + (long)nh * 1024 * 64;
  const unsigned short* vg0 = v_cp + ((long)n * 512 + h * 64) * 1024;
  unsigned short* Pw = &Ps[wv * 16 * 136];

  // DMA staging coords (inverse-swizzled source columns):
  //   K: wave-rows [wv*32,+32), 4 issues x 8 rows; row&7 = lane>>3
  //   V: wave-rows [wv*16,+16), 4 issues x 4 rows; row&7 = (i*4+(lane>>4))&7
  const int krow = lane >> 3;
  const int kcol = ((lane & 7) * 8) ^ ((lane >> 3) * 8);
  const int vrow = lane >> 4;
  const int rsw = (ln & 7) * 8;   // read-side XOR (frag row&7 == ln&7)

  for (int c = 0; c < 8; ++c) {
    const unsigned short* kg = kg0 + (long)c * 128 * 64;
    const unsigned short* vg = vg0 + c * 128;
#pragma unroll
    for (int i = 0; i < 4; ++i) {
      const int vcol = ((lane & 15) * 8) ^ ((((i * 4) + vrow) & 7) * 8);
      gload_lds16(kg + (long)(wv * 32 + i * 8 + krow) * 64 + kcol,
                  &Ks[(wv * 32 + i * 8) * 64]);
      gload_lds16(vg + (long)(wv * 16 + i * 4 + vrow) * 1024 + vcol,
                  &Vs[(wv * 16 + i * 4) * 128]);
    }
    __syncthreads();   // drains vmcnt -> DMA data visible

    bf16x8 ap[2][4];
#pragma unroll
    for (int s2 = 0; s2 < 2; ++s2) {
      // ---- S^T = K Q^T : C row = key (j*16+quad*4+r), col = q (ln) ----
      f32x4 s[8];
#pragma unroll
      for (int j = 0; j < 8; ++j) {
        bf16x8 ka0 = *(const bf16x8*)&Ks[(j * 16 + ln) * 64 + ((quad * 8) ^ rsw)];
        bf16x8 ka1 = *(const bf16x8*)&Ks[(j * 16 + ln) * 64 + ((32 + quad * 8) ^ rsw)];
        f32x4 sj = MFMA16(ka0, qa[s2][0], zero);
        s[j] = MFMA16(ka1, qa[s2][1], sj);
      }
      // ---- p = 2^s (logits pre-scaled by 0.125*log2e) ----
      float ls = 0.f;
#pragma unroll
      for (int j = 0; j < 8; ++j)
#pragma unroll
        for (int r = 0; r < 4; ++r) {
          float pv = __builtin_amdgcn_exp2f(s[j][r]);
          s[j][r] = pv;
          ls += pv;
        }
      l_acc[s2] += ls;
      // ---- P -> wave-private LDS (packed b64), then B-frag reads ----
#pragma unroll
      for (int j = 0; j < 8; ++j) {
        uint2 pk;
        pk.x = __builtin_amdgcn_perm(f32u(s[j][1]), f32u(s[j][0]), 0x07060302u);
        pk.y = __builtin_amdgcn_perm(f32u(s[j][3]), f32u(s[j][2]), 0x07060302u);
        *(uint2*)&Pw[ln * 136 + j * 16 + quad * 4] = pk;
      }
#pragma unroll
      for (int k2 = 0; k2 < 4; ++k2)
        ap[s2][k2] = *(const bf16x8*)&Pw[ln * 136 + k2 * 32 + quad * 8];
    }

    // ---- O^T += V^T P^T : each Vs fragment feeds both sets ----
#pragma unroll
    for (int nf = 0; nf < 4; ++nf)
#pragma unroll
      for (int k2 = 0; k2 < 4; ++k2) {
        bf16x8 va = *(const bf16x8*)&Vs[(nf * 16 + ln) * 128 + ((k2 * 32 + quad * 8) ^ rsw)];
        o_acc[0][nf] = MFMA16(va, ap[0][k2], o_acc[0][nf]);
        o_acc[1][nf] = MFMA16(va, ap[1][k2], o_acc[1][nf]);
      }
    __syncthreads();   // compute done before next chunk's DMA overwrite
  }

#pragma unroll
  for (int s2 = 0; s2 < 2; ++s2) {
    float la = l_acc[s2];
    la += __shfl_xor(la, 16);
    la += __shfl_xor(la, 32);
    float linv = 1.0f / la;
    const int p = q0 + s2 * 64 + wv * 16 + ln;
    unsigned short* yb = y_pc + ((long)n * 1024 + p) * 512 + h * 64 + quad * 4;
#pragma unroll
    for (int nf = 0; nf < 4; ++nf) {
      ushort4 st;
      st.x = f2bf(o_acc[s2][nf][0] * linv);
      st.y = f2bf(o_acc[s2][nf][1] * linv);
      st.z = f2bf(o_acc[s2][nf][2] * linv);
      st.w = f2bf(o_acc[s2][nf][3] * linv);
      *(ushort4*)&yb[nf * 16] = st;
    }
  }
}

// ---------------------------------------------------------------------------
extern "C" void kernel_launch(void* const* d_in, const int* in_sizes, int n_in,
                              void* d_out, int out_size, void* d_ws, size_t ws_size,
                              hipStream_t stream) {
  (void)in_sizes; (void)n_in; (void)out_size; (void)ws_size;
  const float* x     = (const float*)d_in[0];
  const float* qkv_w = (const float*)d_in[1];
  const float* qkv_b = (const float*)d_in[2];
  const float* out_w = (const float*)d_in[3];
  const float* out_b = (const float*)d_in[4];
  const int* de = (const int*)d_in[5];
  float* out = (float*)d_out;
  unsigned short* ws = (unsigned short*)d_ws;

  // ws layout (shorts), ~66 MiB total:
  //   [0, 8388608)            xT, reused as y_pc
  //   [8388608, 33554432)     qkv: q_pd | k_pd | v_cp (8388608 each)
  //   [33554432, 34340864)    wq bf16 (786432)
  //   [34340864, 34603008)    wo bf16 (262144)
  unsigned short* xT   = ws;
  unsigned short* qkv  = ws + 8388608;
  unsigned short* y_pc = ws;
  unsigned short* wq   = ws + 33554432;
  unsigned short* wo   = wq + 786432;

  cvt_bf16<<<3072, 256, 0, stream>>>(qkv_w, wq, 786432);
  cvt_bf16<<<1024, 256, 0, stream>>>(out_w, wo, 262144);

  transpose_cvt<<<dim3(32, 16, 16), 256, 0, stream>>>(x, xT);

  gemm_qkv<<<dim3(12, 8, 16), 256, 0, stream>>>(xT, wq, qkv, qkv_b);

  attn_kernel<<<dim3(8, 128), 256, 0, stream>>>(
      qkv, qkv + 8388608, qkv + 16777216, y_pc);

  gemm_out<<<dim3(4, 8, 16), 256, 0, stream>>>(
      y_pc, wo, out, out_b, x, de);
}

// Round 2
// 206.935 us; speedup vs baseline: 1.1303x; 1.0261x over previous
//
#include <hip/hip_runtime.h>

typedef short bf16x8 __attribute__((ext_vector_type(8)));
typedef float f32x4 __attribute__((ext_vector_type(4)));
typedef float f32x16 __attribute__((ext_vector_type(16)));

#define MFMA16(a,b,c) __builtin_amdgcn_mfma_f32_16x16x32_bf16((a),(b),(c),0,0,0)
#define MFMA32(a,b,c) __builtin_amdgcn_mfma_f32_32x32x16_bf16((a),(b),(c),0,0,0)

static __device__ __forceinline__ unsigned short f2bf(float f){
  unsigned u; __builtin_memcpy(&u, &f, 4);
  u += 0x7fffu + ((u >> 16) & 1u);
  return (unsigned short)(u >> 16);
}

// v_cvt_pk_bf16_f32: D = {lo: bf16(lo), hi: bf16(hi)}  (no builtin on gfx950)
static __device__ __forceinline__ unsigned cvtpk(float lo, float hi){
  unsigned r;
  asm volatile("v_cvt_pk_bf16_f32 %0, %1, %2" : "=v"(r) : "v"(lo), "v"(hi));
  return r;
}
// v_permlane32_swap_b32 a, b:  a[l<32]=b_old[l+32]; b[l>=32]=a_old[l-32]
static __device__ __forceinline__ void pl32swap(unsigned &a, unsigned &b){
  asm volatile("v_permlane32_swap_b32 %0, %1" : "+v"(a), "+v"(b));
}

// async global->LDS DMA, 16 B per lane; LDS dest = wave-uniform base + lane*16
static __device__ __forceinline__ void gload_lds16(const void* g, void* l) {
  __builtin_amdgcn_global_load_lds(
      (__attribute__((address_space(1))) void*)g,
      (__attribute__((address_space(3))) void*)l, 16, 0, 0);
}

// ---------------------------------------------------------------------------
// Stage f32 tensor -> bf16.
// ---------------------------------------------------------------------------
__global__ __launch_bounds__(256) void cvt_bf16(
    const float* __restrict__ in, unsigned short* __restrict__ out, int n) {
  int i = blockIdx.x * 256 + threadIdx.x;
  if (i < n) out[i] = f2bf(in[i]);
}

// ---------------------------------------------------------------------------
// T0: x [n][512 c][1024 p] f32 -> xT [n][1024 p][512 c] bf16
// ---------------------------------------------------------------------------
__global__ __launch_bounds__(256) void transpose_cvt(
    const float* __restrict__ in, unsigned short* __restrict__ out)
{
  __shared__ unsigned short tile[32][33];
  const long base = (long)blockIdx.z * 512 * 1024;
  const int t = threadIdx.x, tx = t & 31, ty = t >> 5;
  const int c0 = blockIdx.x * 32, r0 = blockIdx.y * 32;
  const float* ib = in + base;
#pragma unroll
  for (int i = 0; i < 4; ++i)
    tile[ty + i * 8][tx] = f2bf(ib[(long)(r0 + ty + i * 8) * 1024 + c0 + tx]);
  __syncthreads();
  unsigned short* ob = out + base;
#pragma unroll
  for (int i = 0; i < 4; ++i)
    ob[(long)(c0 + ty + i * 8) * 512 + r0 + tx] = tile[tx][ty + i * 8];
}

// ---------------------------------------------------------------------------
// K1: QKV GEMM (global_load_lds staging, XOR-swizzled LDS tiles).
// ---------------------------------------------------------------------------
__global__ __launch_bounds__(256, 3) void gemm_qkv(
    const unsigned short* __restrict__ A, const unsigned short* __restrict__ B,
    unsigned short* __restrict__ qkvout, const float* __restrict__ bias)
{
  const int M = 1024, K = 512;
  __shared__ unsigned short As[128 * 64];
  __shared__ unsigned short Bs[128 * 64];
  const int t = threadIdx.x, lane = t & 63, wv = t >> 6;
  const int quad = lane >> 4, ln = lane & 15;
  const int m0 = blockIdx.y * 128, n0 = blockIdx.x * 128;
  const long zb = blockIdx.z;
  A += zb * (long)M * K;

  const int srow = wv * 32 + (lane >> 3);
  const int scol = ((lane & 7) * 8) ^ ((lane >> 3) * 8);

  f32x4 zero = {0.f, 0.f, 0.f, 0.f};
  f32x4 acc[4][4];
#pragma unroll
  for (int i = 0; i < 4; ++i)
#pragma unroll
    for (int j = 0; j < 4; ++j) acc[i][j] = zero;

  const int wm = (wv & 1) * 64, wn = (wv >> 1) * 64;
  const int rsw = (ln & 7) * 8;

  for (int kt = 0; kt < K; kt += 64) {
#pragma unroll
    for (int i = 0; i < 4; ++i) {
      gload_lds16(&A[(long)(m0 + srow + i * 8) * K + kt + scol],
                  &As[(wv * 32 + i * 8) * 64]);
      gload_lds16(&B[(long)(n0 + srow + i * 8) * K + kt + scol],
                  &Bs[(wv * 32 + i * 8) * 64]);
    }
    __syncthreads();
#pragma unroll
    for (int kk = 0; kk < 64; kk += 32) {
      bf16x8 a[4], b[4];
#pragma unroll
      for (int i = 0; i < 4; ++i)
        a[i] = *(const bf16x8*)&As[(wm + i * 16 + ln) * 64 + ((kk + quad * 8) ^ rsw)];
#pragma unroll
      for (int j = 0; j < 4; ++j)
        b[j] = *(const bf16x8*)&Bs[(wn + j * 16 + ln) * 64 + ((kk + quad * 8) ^ rsw)];
#pragma unroll
      for (int i = 0; i < 4; ++i)
#pragma unroll
        for (int j = 0; j < 4; ++j)
          acc[i][j] = MFMA16(a[i], b[j], acc[i][j]);
    }
    __syncthreads();
  }

#pragma unroll
  for (int j = 0; j < 4; ++j) {
    int o = n0 + wn + j * 16 + ln;
    float bb = bias[o];
    int part = o >> 9;          // 0=q, 1=k, 2=v
    int h = (o >> 6) & 7, d = o & 63;
    float qs = (part == 0) ? 0.18033688f : 1.0f;  // 0.125 * log2(e)
#pragma unroll
    for (int i = 0; i < 4; ++i) {
      int p = m0 + wm + i * 16 + quad * 4;
      f32x4 v = acc[i][j];
      if (part < 2) {
        unsigned short* dst = qkvout + (long)part * 8388608
            + ((long)(zb * 8 + h) * 1024 + p) * 64 + d;
#pragma unroll
        for (int r = 0; r < 4; ++r) dst[r * 64] = f2bf((v[r] + bb) * qs);
      } else {
        long cidx = ((long)zb * 512 + (o - 1024)) * 1024 + p;
        ushort4 st;
        st.x = f2bf(v[0] + bb); st.y = f2bf(v[1] + bb);
        st.z = f2bf(v[2] + bb); st.w = f2bf(v[3] + bb);
        *(ushort4*)&qkvout[16777216 + cidx] = st;
      }
    }
  }
}

// ---------------------------------------------------------------------------
// K3: OUT GEMM (same staging/swizzle) + bias + dropout-scale + residual; f32.
// ---------------------------------------------------------------------------
__global__ __launch_bounds__(256, 3) void gemm_out(
    const unsigned short* __restrict__ A, const unsigned short* __restrict__ B,
    float* __restrict__ C, const float* __restrict__ bias,
    const float* __restrict__ xin, const int* __restrict__ de_ptr)
{
  const int M = 1024, K = 512;
  __shared__ unsigned short As[128 * 64];
  __shared__ unsigned short Bs[128 * 64];
  const int t = threadIdx.x, lane = t & 63, wv = t >> 6;
  const int quad = lane >> 4, ln = lane & 15;
  const int m0 = blockIdx.y * 128, n0 = blockIdx.x * 128;
  const long zb = blockIdx.z;
  A += zb * (long)M * K;
  C += zb * 512l * M;
  xin += zb * 512l * M;

  const int srow = wv * 32 + (lane >> 3);
  const int scol = ((lane & 7) * 8) ^ ((lane >> 3) * 8);

  f32x4 zero = {0.f, 0.f, 0.f, 0.f};
  f32x4 acc[4][4];
#pragma unroll
  for (int i = 0; i < 4; ++i)
#pragma unroll
    for (int j = 0; j < 4; ++j) acc[i][j] = zero;

  const int wm = (wv & 1) * 64, wn = (wv >> 1) * 64;
  const int rsw = (ln & 7) * 8;

  for (int kt = 0; kt < K; kt += 64) {
#pragma unroll
    for (int i = 0; i < 4; ++i) {
      gload_lds16(&A[(long)(m0 + srow + i * 8) * K + kt + scol],
                  &As[(wv * 32 + i * 8) * 64]);
      gload_lds16(&B[(long)(n0 + srow + i * 8) * K + kt + scol],
                  &Bs[(wv * 32 + i * 8) * 64]);
    }
    __syncthreads();
#pragma unroll
    for (int kk = 0; kk < 64; kk += 32) {
      bf16x8 a[4], b[4];
#pragma unroll
      for (int i = 0; i < 4; ++i)
        a[i] = *(const bf16x8*)&As[(wm + i * 16 + ln) * 64 + ((kk + quad * 8) ^ rsw)];
#pragma unroll
      for (int j = 0; j < 4; ++j)
        b[j] = *(const bf16x8*)&Bs[(wn + j * 16 + ln) * 64 + ((kk + quad * 8) ^ rsw)];
#pragma unroll
      for (int i = 0; i < 4; ++i)
#pragma unroll
        for (int j = 0; j < 4; ++j)
          acc[i][j] = MFMA16(a[i], b[j], acc[i][j]);
    }
    __syncthreads();
  }

  float dscale = 1.0f / (1.0f - 0.1f * (float)de_ptr[0]);

#pragma unroll
  for (int j = 0; j < 4; ++j) {
    int o = n0 + wn + j * 16 + ln;
    float bb = bias[o];
#pragma unroll
    for (int i = 0; i < 4; ++i) {
      int p = m0 + wm + i * 16 + quad * 4;
      long cidx = (long)o * M + p;
      f32x4 v = acc[i][j];
      float4 rx = *(const float4*)&xin[cidx];
      float4 st;
      st.x = rx.x + (v[0] + bb) * dscale;
      st.y = rx.y + (v[1] + bb) * dscale;
      st.z = rx.z + (v[2] + bb) * dscale;
      st.w = rx.w + (v[3] + bb) * dscale;
      *(float4*)&C[cidx] = st;
    }
  }
}

// ---------------------------------------------------------------------------
// Flash attention v7: 32x32x16 MFMA, 256 q-rows/block, in-register P via
// cvt_pk_bf16 + permlane32_swap (no Ps LDS round trip), double-buffered K/V
// staging via global_load_lds, XCD-grouping block swizzle.
//
// Wave owns 64 q (2 q-groups of 32). S^T tile (32 key x 32 q): C col=q=lane&31,
// row=key=(r&3)+8*(r>>2)+4*(lane>>5). P^T B-frag for PV needs lane<->lane+32
// exchange only: op(A=pk_odd, B=pk_even) -> dw0,1=B', dw2,3=A'.
// ---------------------------------------------------------------------------
__global__ __launch_bounds__(256, 2) void attn_kernel(
    const unsigned short* __restrict__ q_pd, const unsigned short* __restrict__ k_pd,
    const unsigned short* __restrict__ v_cp, unsigned short* __restrict__ y_pc)
{
  __shared__ unsigned short Ks[2][128 * 64];     // 2 x 16 KB, DMA dest
  __shared__ unsigned short Vs[2][64 * 128];     // 2 x 16 KB, DMA dest
  const int t = threadIdx.x, lane = t & 63, wv = t >> 6;
  const int l31 = lane & 31, bh8 = (lane >> 5) * 8;
  // XCD-grouping swizzle: 4 q-tile blocks sharing (n,h) get equal (id%8).
  const int qt = blockIdx.y >> 5;                     // 0..3 q-tile
  const int nh = blockIdx.x * 32 + (blockIdx.y & 31); // 0..127
  const int n = nh >> 3, h = nh & 7;
  const int q0 = qt * 256;

  // Q fragments (B-operand, 32x32x16): n=q=l31, k=d=ds*16+bh8+j. Pre-scaled.
  bf16x8 qa[2][4];
#pragma unroll
  for (int qg = 0; qg < 2; ++qg) {
    const unsigned short* qb =
        q_pd + ((long)nh * 1024 + q0 + wv * 64 + qg * 32 + l31) * 64;
#pragma unroll
    for (int ds = 0; ds < 4; ++ds)
      qa[qg][ds] = *(const bf16x8*)(qb + ds * 16 + bh8);
  }

  f32x16 zacc;
#pragma unroll
  for (int r = 0; r < 16; ++r) zacc[r] = 0.f;
  f32x16 o_acc[2][2];
  o_acc[0][0] = zacc; o_acc[0][1] = zacc; o_acc[1][0] = zacc; o_acc[1][1] = zacc;
  float l_acc[2] = {0.f, 0.f};

  const unsigned short* kg0 = k_pd + (long)nh * 1024 * 64;
  const unsigned short* vg0 = v_cp + ((long)n * 512 + h * 64) * 1024;

  // DMA staging coords (inverse-swizzled source columns; LDS dest linear):
  const int krow = lane >> 3;
  const int kcol = ((lane & 7) * 8) ^ ((lane >> 3) * 8);
  const int vrow = lane >> 4;
  const int rsw = (lane & 7) * 8;   // read-side XOR (frag row&7 == lane&7)

  // prologue: stage chunk 0 into buffer 0
#pragma unroll
  for (int i = 0; i < 4; ++i) {
    const int vcol = ((lane & 15) * 8) ^ ((((i * 4) + vrow) & 7) * 8);
    gload_lds16(kg0 + (long)(wv * 32 + i * 8 + krow) * 64 + kcol,
                &Ks[0][(wv * 32 + i * 8) * 64]);
    gload_lds16(vg0 + (long)(wv * 16 + i * 4 + vrow) * 1024 + vcol,
                &Vs[0][(wv * 16 + i * 4) * 128]);
  }
  __syncthreads();

  // softmax+pack: exp2, row-sum, cvt_pk pairs, permlane32 swaps -> 2 B-frags
  union U { bf16x8 v; unsigned u[4]; };
  auto sm_pack = [&](const f32x16& sv, bf16x8* paq, float& lac) {
    float e[16];
#pragma unroll
    for (int r = 0; r < 16; ++r) e[r] = __builtin_amdgcn_exp2f(sv[r]);
    float ls = 0.f;
#pragma unroll
    for (int r = 0; r < 16; ++r) ls += e[r];
    lac += ls;
    unsigned pk4[4][2];
#pragma unroll
    for (int hh = 0; hh < 4; ++hh) {
      pk4[hh][0] = cvtpk(e[4 * hh + 0], e[4 * hh + 1]);
      pk4[hh][1] = cvtpk(e[4 * hh + 2], e[4 * hh + 3]);
    }
#pragma unroll
    for (int hk = 0; hk < 2; ++hk) {
      unsigned a0 = pk4[2 * hk + 1][0], b0 = pk4[2 * hk][0];
      unsigned a1 = pk4[2 * hk + 1][1], b1 = pk4[2 * hk][1];
      pl32swap(a0, b0); pl32swap(a1, b1);
      U u; u.u[0] = b0; u.u[1] = b1; u.u[2] = a0; u.u[3] = a1;
      paq[hk] = u.v;
    }
  };

  for (int c = 0; c < 8; ++c) {
    const int cur = c & 1;
    if (c < 7) {   // stage next chunk into the other buffer (overlaps compute)
      const unsigned short* kg = kg0 + (long)(c + 1) * 128 * 64;
      const unsigned short* vg = vg0 + (c + 1) * 128;
      unsigned short* KsD = Ks[cur ^ 1];
      unsigned short* VsD = Vs[cur ^ 1];
#pragma unroll
      for (int i = 0; i < 4; ++i) {
        const int vcol = ((lane & 15) * 8) ^ ((((i * 4) + vrow) & 7) * 8);
        gload_lds16(kg + (long)(wv * 32 + i * 8 + krow) * 64 + kcol,
                    &KsD[(wv * 32 + i * 8) * 64]);
        gload_lds16(vg + (long)(wv * 16 + i * 4 + vrow) * 1024 + vcol,
                    &VsD[(wv * 16 + i * 4) * 128]);
      }
    }
    const unsigned short* KsC = Ks[cur];
    const unsigned short* VsC = Vs[cur];

#pragma unroll
    for (int kgi = 0; kgi < 4; ++kgi) {
      // ---- S^T = K Q^T over 32-key group kgi ----
      f32x16 s0 = zacc, s1 = zacc;
#pragma unroll
      for (int ds = 0; ds < 4; ++ds) {
        bf16x8 ka = *(const bf16x8*)&KsC[(kgi * 32 + l31) * 64 + ((ds * 16 + bh8) ^ rsw)];
        s0 = MFMA32(ka, qa[0][ds], s0);
        s1 = MFMA32(ka, qa[1][ds], s1);
      }
      // ---- softmax partial + in-register P^T B-frags ----
      bf16x8 pa[2][2];
      sm_pack(s0, pa[0], l_acc[0]);
      sm_pack(s1, pa[1], l_acc[1]);
      // ---- O^T += V^T P^T for this key group ----
#pragma unroll
      for (int dg = 0; dg < 2; ++dg)
#pragma unroll
        for (int hk = 0; hk < 2; ++hk) {
          bf16x8 va = *(const bf16x8*)
              &VsC[(dg * 32 + l31) * 128 + (((kgi * 2 + hk) * 16 + bh8) ^ rsw)];
          o_acc[dg][0] = MFMA32(va, pa[0][hk], o_acc[dg][0]);
          o_acc[dg][1] = MFMA32(va, pa[1][hk], o_acc[dg][1]);
        }
    }
    __syncthreads();   // drains staged DMA (vmcnt) + all waves done with KsC/VsC
  }

  // ---- epilogue: normalize, store y_pc [n][p=q][c = h*64 + d] ----
#pragma unroll
  for (int qg = 0; qg < 2; ++qg) {
    float la = l_acc[qg];
    la += __shfl_xor(la, 32);
    float linv = 1.0f / la;
    const int q = q0 + wv * 64 + qg * 32 + l31;
    unsigned short* yb = y_pc + ((long)n * 1024 + q) * 512 + h * 64;
#pragma unroll
    for (int dg = 0; dg < 2; ++dg) {
      f32x16 o = o_acc[dg][qg];
#pragma unroll
      for (int rq = 0; rq < 4; ++rq) {
        int d0 = dg * 32 + rq * 8 + (bh8 >> 1);   // (lane>>5)*4
        ushort4 st;
        st.x = f2bf(o[rq * 4 + 0] * linv);
        st.y = f2bf(o[rq * 4 + 1] * linv);
        st.z = f2bf(o[rq * 4 + 2] * linv);
        st.w = f2bf(o[rq * 4 + 3] * linv);
        *(ushort4*)&yb[d0] = st;
      }
    }
  }
}

// ---------------------------------------------------------------------------
extern "C" void kernel_launch(void* const* d_in, const int* in_sizes, int n_in,
                              void* d_out, int out_size, void* d_ws, size_t ws_size,
                              hipStream_t stream) {
  (void)in_sizes; (void)n_in; (void)out_size; (void)ws_size;
  const float* x     = (const float*)d_in[0];
  const float* qkv_w = (const float*)d_in[1];
  const float* qkv_b = (const float*)d_in[2];
  const float* out_w = (const float*)d_in[3];
  const float* out_b = (const float*)d_in[4];
  const int* de = (const int*)d_in[5];
  float* out = (float*)d_out;
  unsigned short* ws = (unsigned short*)d_ws;

  // ws layout (shorts), ~66 MiB total:
  //   [0, 8388608)            xT, reused as y_pc
  //   [8388608, 33554432)     qkv: q_pd | k_pd | v_cp (8388608 each)
  //   [33554432, 34340864)    wq bf16 (786432)
  //   [34340864, 34603008)    wo bf16 (262144)
  unsigned short* xT   = ws;
  unsigned short* qkv  = ws + 8388608;
  unsigned short* y_pc = ws;
  unsigned short* wq   = ws + 33554432;
  unsigned short* wo   = wq + 786432;

  cvt_bf16<<<3072, 256, 0, stream>>>(qkv_w, wq, 786432);
  cvt_bf16<<<1024, 256, 0, stream>>>(out_w, wo, 262144);

  transpose_cvt<<<dim3(32, 16, 16), 256, 0, stream>>>(x, xT);

  gemm_qkv<<<dim3(12, 8, 16), 256, 0, stream>>>(xT, wq, qkv, qkv_b);

  attn_kernel<<<dim3(4, 128), 256, 0, stream>>>(
      qkv, qkv + 8388608, qkv + 16777216, y_pc);

  gemm_out<<<dim3(4, 8, 16), 256, 0, stream>>>(
      y_pc, wo, out, out_b, x, de);
}

// Round 3
// 191.258 us; speedup vs baseline: 1.2230x; 1.0820x over previous
//
#include <hip/hip_runtime.h>

typedef short bf16x8 __attribute__((ext_vector_type(8)));
typedef float f32x4 __attribute__((ext_vector_type(4)));
typedef float f32x16 __attribute__((ext_vector_type(16)));

#define MFMA16(a,b,c) __builtin_amdgcn_mfma_f32_16x16x32_bf16((a),(b),(c),0,0,0)
#define MFMA32(a,b,c) __builtin_amdgcn_mfma_f32_32x32x16_bf16((a),(b),(c),0,0,0)

static __device__ __forceinline__ unsigned short f2bf(float f){
  unsigned u; __builtin_memcpy(&u, &f, 4);
  u += 0x7fffu + ((u >> 16) & 1u);
  return (unsigned short)(u >> 16);
}

// v_cvt_pk_bf16_f32: D = {lo: bf16(lo), hi: bf16(hi)}  (no builtin on gfx950)
static __device__ __forceinline__ unsigned cvtpk(float lo, float hi){
  unsigned r;
  asm volatile("v_cvt_pk_bf16_f32 %0, %1, %2" : "=v"(r) : "v"(lo), "v"(hi));
  return r;
}
// v_permlane32_swap_b32 a, b:  a[l<32]=b_old[l+32]; b[l>=32]=a_old[l-32]
static __device__ __forceinline__ void pl32swap(unsigned &a, unsigned &b){
  asm volatile("v_permlane32_swap_b32 %0, %1" : "+v"(a), "+v"(b));
}

// async global->LDS DMA, 16 B per lane; LDS dest = wave-uniform base + lane*16
static __device__ __forceinline__ void gload_lds16(const void* g, void* l) {
  __builtin_amdgcn_global_load_lds(
      (__attribute__((address_space(1))) void*)g,
      (__attribute__((address_space(3))) void*)l, 16, 0, 0);
}

// ---------------------------------------------------------------------------
// Stage f32 tensor -> bf16.
// ---------------------------------------------------------------------------
__global__ __launch_bounds__(256) void cvt_bf16(
    const float* __restrict__ in, unsigned short* __restrict__ out, int n) {
  int i = blockIdx.x * 256 + threadIdx.x;
  if (i < n) out[i] = f2bf(in[i]);
}

// ---------------------------------------------------------------------------
// T0: x [n][512 c][1024 p] f32 -> xT [n][1024 p][512 c] bf16
// ---------------------------------------------------------------------------
__global__ __launch_bounds__(256) void transpose_cvt(
    const float* __restrict__ in, unsigned short* __restrict__ out)
{
  __shared__ unsigned short tile[32][33];
  const long base = (long)blockIdx.z * 512 * 1024;
  const int t = threadIdx.x, tx = t & 31, ty = t >> 5;
  const int c0 = blockIdx.x * 32, r0 = blockIdx.y * 32;
  const float* ib = in + base;
#pragma unroll
  for (int i = 0; i < 4; ++i)
    tile[ty + i * 8][tx] = f2bf(ib[(long)(r0 + ty + i * 8) * 1024 + c0 + tx]);
  __syncthreads();
  unsigned short* ob = out + base;
#pragma unroll
  for (int i = 0; i < 4; ++i)
    ob[(long)(c0 + ty + i * 8) * 512 + r0 + tx] = tile[tx][ty + i * 8];
}

// ---------------------------------------------------------------------------
// K1: QKV GEMM (global_load_lds staging, XOR-swizzled LDS tiles).
// XCD-grouped block remap: each XCD (id%8) owns 2 whole batches, so the
// A-panels (2 MB) + B (1.5 MB) live in its private 4 MB L2.
// ---------------------------------------------------------------------------
__global__ __launch_bounds__(256, 3) void gemm_qkv(
    const unsigned short* __restrict__ A, const unsigned short* __restrict__ B,
    unsigned short* __restrict__ qkvout, const float* __restrict__ bias)
{
  const int M = 1024, K = 512;
  __shared__ unsigned short As[128 * 64];
  __shared__ unsigned short Bs[128 * 64];
  const int t = threadIdx.x, lane = t & 63, wv = t >> 6;
  const int quad = lane >> 4, ln = lane & 15;

  // bijective XCD remap: L in [0,1536), v = (L%8)*192 + L/8
  const int L = blockIdx.x + 12 * blockIdx.y + 96 * blockIdx.z;
  const int v = (L & 7) * 192 + (L >> 3);
  const int m0 = ((v / 12) & 7) * 128, n0 = (v % 12) * 128;
  const long zb = v / 96;
  A += zb * (long)M * K;

  const int srow = wv * 32 + (lane >> 3);
  const int scol = ((lane & 7) * 8) ^ ((lane >> 3) * 8);

  f32x4 zero = {0.f, 0.f, 0.f, 0.f};
  f32x4 acc[4][4];
#pragma unroll
  for (int i = 0; i < 4; ++i)
#pragma unroll
    for (int j = 0; j < 4; ++j) acc[i][j] = zero;

  const int wm = (wv & 1) * 64, wn = (wv >> 1) * 64;
  const int rsw = (ln & 7) * 8;

  for (int kt = 0; kt < K; kt += 64) {
#pragma unroll
    for (int i = 0; i < 4; ++i) {
      gload_lds16(&A[(long)(m0 + srow + i * 8) * K + kt + scol],
                  &As[(wv * 32 + i * 8) * 64]);
      gload_lds16(&B[(long)(n0 + srow + i * 8) * K + kt + scol],
                  &Bs[(wv * 32 + i * 8) * 64]);
    }
    __syncthreads();
#pragma unroll
    for (int kk = 0; kk < 64; kk += 32) {
      bf16x8 a[4], b[4];
#pragma unroll
      for (int i = 0; i < 4; ++i)
        a[i] = *(const bf16x8*)&As[(wm + i * 16 + ln) * 64 + ((kk + quad * 8) ^ rsw)];
#pragma unroll
      for (int j = 0; j < 4; ++j)
        b[j] = *(const bf16x8*)&Bs[(wn + j * 16 + ln) * 64 + ((kk + quad * 8) ^ rsw)];
#pragma unroll
      for (int i = 0; i < 4; ++i)
#pragma unroll
        for (int j = 0; j < 4; ++j)
          acc[i][j] = MFMA16(a[i], b[j], acc[i][j]);
    }
    __syncthreads();
  }

#pragma unroll
  for (int j = 0; j < 4; ++j) {
    int o = n0 + wn + j * 16 + ln;
    float bb = bias[o];
    int part = o >> 9;          // 0=q, 1=k, 2=v
    int h = (o >> 6) & 7, d = o & 63;
    float qs = (part == 0) ? 0.18033688f : 1.0f;  // 0.125 * log2(e)
#pragma unroll
    for (int i = 0; i < 4; ++i) {
      int p = m0 + wm + i * 16 + quad * 4;
      f32x4 vv = acc[i][j];
      if (part < 2) {
        unsigned short* dst = qkvout + (long)part * 8388608
            + ((long)(zb * 8 + h) * 1024 + p) * 64 + d;
#pragma unroll
        for (int r = 0; r < 4; ++r) dst[r * 64] = f2bf((vv[r] + bb) * qs);
      } else {
        long cidx = ((long)zb * 512 + (o - 1024)) * 1024 + p;
        ushort4 st;
        st.x = f2bf(vv[0] + bb); st.y = f2bf(vv[1] + bb);
        st.z = f2bf(vv[2] + bb); st.w = f2bf(vv[3] + bb);
        *(ushort4*)&qkvout[16777216 + cidx] = st;
      }
    }
  }
}

// ---------------------------------------------------------------------------
// K3: OUT GEMM (same staging/swizzle + XCD remap) + bias + dropout + residual.
// ---------------------------------------------------------------------------
__global__ __launch_bounds__(256, 3) void gemm_out(
    const unsigned short* __restrict__ A, const unsigned short* __restrict__ B,
    float* __restrict__ C, const float* __restrict__ bias,
    const float* __restrict__ xin, const int* __restrict__ de_ptr)
{
  const int M = 1024, K = 512;
  __shared__ unsigned short As[128 * 64];
  __shared__ unsigned short Bs[128 * 64];
  const int t = threadIdx.x, lane = t & 63, wv = t >> 6;
  const int quad = lane >> 4, ln = lane & 15;

  // bijective XCD remap: L in [0,512), v = (L%8)*64 + L/8
  const int L = blockIdx.x + 4 * blockIdx.y + 32 * blockIdx.z;
  const int v = (L & 7) * 64 + (L >> 3);
  const int m0 = ((v >> 2) & 7) * 128, n0 = (v & 3) * 128;
  const long zb = v >> 5;
  A += zb * (long)M * K;
  C += zb * 512l * M;
  xin += zb * 512l * M;

  const int srow = wv * 32 + (lane >> 3);
  const int scol = ((lane & 7) * 8) ^ ((lane >> 3) * 8);

  f32x4 zero = {0.f, 0.f, 0.f, 0.f};
  f32x4 acc[4][4];
#pragma unroll
  for (int i = 0; i < 4; ++i)
#pragma unroll
    for (int j = 0; j < 4; ++j) acc[i][j] = zero;

  const int wm = (wv & 1) * 64, wn = (wv >> 1) * 64;
  const int rsw = (ln & 7) * 8;

  for (int kt = 0; kt < K; kt += 64) {
#pragma unroll
    for (int i = 0; i < 4; ++i) {
      gload_lds16(&A[(long)(m0 + srow + i * 8) * K + kt + scol],
                  &As[(wv * 32 + i * 8) * 64]);
      gload_lds16(&B[(long)(n0 + srow + i * 8) * K + kt + scol],
                  &Bs[(wv * 32 + i * 8) * 64]);
    }
    __syncthreads();
#pragma unroll
    for (int kk = 0; kk < 64; kk += 32) {
      bf16x8 a[4], b[4];
#pragma unroll
      for (int i = 0; i < 4; ++i)
        a[i] = *(const bf16x8*)&As[(wm + i * 16 + ln) * 64 + ((kk + quad * 8) ^ rsw)];
#pragma unroll
      for (int j = 0; j < 4; ++j)
        b[j] = *(const bf16x8*)&Bs[(wn + j * 16 + ln) * 64 + ((kk + quad * 8) ^ rsw)];
#pragma unroll
      for (int i = 0; i < 4; ++i)
#pragma unroll
        for (int j = 0; j < 4; ++j)
          acc[i][j] = MFMA16(a[i], b[j], acc[i][j]);
    }
    __syncthreads();
  }

  float dscale = 1.0f / (1.0f - 0.1f * (float)de_ptr[0]);

#pragma unroll
  for (int j = 0; j < 4; ++j) {
    int o = n0 + wn + j * 16 + ln;
    float bb = bias[o];
#pragma unroll
    for (int i = 0; i < 4; ++i) {
      int p = m0 + wm + i * 16 + quad * 4;
      long cidx = (long)o * M + p;
      f32x4 vv = acc[i][j];
      float4 rx = *(const float4*)&xin[cidx];
      float4 st;
      st.x = rx.x + (vv[0] + bb) * dscale;
      st.y = rx.y + (vv[1] + bb) * dscale;
      st.z = rx.z + (vv[2] + bb) * dscale;
      st.w = rx.w + (vv[3] + bb) * dscale;
      *(float4*)&C[cidx] = st;
    }
  }
}

// ---------------------------------------------------------------------------
// Flash attention v8: v7 + wider Vs swizzle (chunk ^= row&15; Vs rows are
// 256 B so bank = f(col) only -> row&7 left a 4-way alias) + s_setprio(1)
// around the MFMA clusters (T5: waves at different phases, no lockstep).
// ---------------------------------------------------------------------------
__global__ __launch_bounds__(256, 2) void attn_kernel(
    const unsigned short* __restrict__ q_pd, const unsigned short* __restrict__ k_pd,
    const unsigned short* __restrict__ v_cp, unsigned short* __restrict__ y_pc)
{
  __shared__ unsigned short Ks[2][128 * 64];     // 2 x 16 KB, DMA dest
  __shared__ unsigned short Vs[2][64 * 128];     // 2 x 16 KB, DMA dest
  const int t = threadIdx.x, lane = t & 63, wv = t >> 6;
  const int l31 = lane & 31, bh8 = (lane >> 5) * 8;
  // XCD-grouping swizzle: 4 q-tile blocks sharing (n,h) get equal (id%8).
  const int qt = blockIdx.y >> 5;                     // 0..3 q-tile
  const int nh = blockIdx.x * 32 + (blockIdx.y & 31); // 0..127
  const int n = nh >> 3, h = nh & 7;
  const int q0 = qt * 256;

  // Q fragments (B-operand, 32x32x16): n=q=l31, k=d=ds*16+bh8+j. Pre-scaled.
  bf16x8 qa[2][4];
#pragma unroll
  for (int qg = 0; qg < 2; ++qg) {
    const unsigned short* qb =
        q_pd + ((long)nh * 1024 + q0 + wv * 64 + qg * 32 + l31) * 64;
#pragma unroll
    for (int ds = 0; ds < 4; ++ds)
      qa[qg][ds] = *(const bf16x8*)(qb + ds * 16 + bh8);
  }

  f32x16 zacc;
#pragma unroll
  for (int r = 0; r < 16; ++r) zacc[r] = 0.f;
  f32x16 o_acc[2][2];
  o_acc[0][0] = zacc; o_acc[0][1] = zacc; o_acc[1][0] = zacc; o_acc[1][1] = zacc;
  float l_acc[2] = {0.f, 0.f};

  const unsigned short* kg0 = k_pd + (long)nh * 1024 * 64;
  const unsigned short* vg0 = v_cp + ((long)n * 512 + h * 64) * 1024;

  // DMA staging coords (inverse-swizzled source columns; LDS dest linear):
  const int krow = lane >> 3;
  const int kcol = ((lane & 7) * 8) ^ ((lane >> 3) * 8);
  const int vrow = lane >> 4;
  const int rsw = (lane & 7) * 8;     // K read XOR (frag row&7 == lane&7)
  const int vrsw = (l31 & 15) * 8;    // V read XOR (frag row&15 == l31&15)

  // prologue: stage chunk 0 into buffer 0
#pragma unroll
  for (int i = 0; i < 4; ++i) {
    const int vr = i * 4 + vrow;                        // row & 15
    const int vcol = ((lane & 15) ^ vr) * 8;
    gload_lds16(kg0 + (long)(wv * 32 + i * 8 + krow) * 64 + kcol,
                &Ks[0][(wv * 32 + i * 8) * 64]);
    gload_lds16(vg0 + (long)(wv * 16 + vr) * 1024 + vcol,
                &Vs[0][(wv * 16 + i * 4) * 128]);
  }
  __syncthreads();

  // softmax+pack: exp2, row-sum, cvt_pk pairs, permlane32 swaps -> 2 B-frags
  union U { bf16x8 v; unsigned u[4]; };
  auto sm_pack = [&](const f32x16& sv, bf16x8* paq, float& lac) {
    float e[16];
#pragma unroll
    for (int r = 0; r < 16; ++r) e[r] = __builtin_amdgcn_exp2f(sv[r]);
    float ls = 0.f;
#pragma unroll
    for (int r = 0; r < 16; ++r) ls += e[r];
    lac += ls;
    unsigned pk4[4][2];
#pragma unroll
    for (int hh = 0; hh < 4; ++hh) {
      pk4[hh][0] = cvtpk(e[4 * hh + 0], e[4 * hh + 1]);
      pk4[hh][1] = cvtpk(e[4 * hh + 2], e[4 * hh + 3]);
    }
#pragma unroll
    for (int hk = 0; hk < 2; ++hk) {
      unsigned a0 = pk4[2 * hk + 1][0], b0 = pk4[2 * hk][0];
      unsigned a1 = pk4[2 * hk + 1][1], b1 = pk4[2 * hk][1];
      pl32swap(a0, b0); pl32swap(a1, b1);
      U u; u.u[0] = b0; u.u[1] = b1; u.u[2] = a0; u.u[3] = a1;
      paq[hk] = u.v;
    }
  };

  for (int c = 0; c < 8; ++c) {
    const int cur = c & 1;
    if (c < 7) {   // stage next chunk into the other buffer (overlaps compute)
      const unsigned short* kg = kg0 + (long)(c + 1) * 128 * 64;
      const unsigned short* vg = vg0 + (c + 1) * 128;
      unsigned short* KsD = Ks[cur ^ 1];
      unsigned short* VsD = Vs[cur ^ 1];
#pragma unroll
      for (int i = 0; i < 4; ++i) {
        const int vr = i * 4 + vrow;
        const int vcol = ((lane & 15) ^ vr) * 8;
        gload_lds16(kg + (long)(wv * 32 + i * 8 + krow) * 64 + kcol,
                    &KsD[(wv * 32 + i * 8) * 64]);
        gload_lds16(vg + (long)(wv * 16 + vr) * 1024 + vcol,
                    &VsD[(wv * 16 + i * 4) * 128]);
      }
    }
    const unsigned short* KsC = Ks[cur];
    const unsigned short* VsC = Vs[cur];

#pragma unroll
    for (int kgi = 0; kgi < 4; ++kgi) {
      // ---- S^T = K Q^T over 32-key group kgi ----
      f32x16 s0 = zacc, s1 = zacc;
      __builtin_amdgcn_s_setprio(1);
#pragma unroll
      for (int ds = 0; ds < 4; ++ds) {
        bf16x8 ka = *(const bf16x8*)&KsC[(kgi * 32 + l31) * 64 + ((ds * 16 + bh8) ^ rsw)];
        s0 = MFMA32(ka, qa[0][ds], s0);
        s1 = MFMA32(ka, qa[1][ds], s1);
      }
      __builtin_amdgcn_s_setprio(0);
      // ---- softmax partial + in-register P^T B-frags ----
      bf16x8 pa[2][2];
      sm_pack(s0, pa[0], l_acc[0]);
      sm_pack(s1, pa[1], l_acc[1]);
      // ---- O^T += V^T P^T for this key group ----
      __builtin_amdgcn_s_setprio(1);
#pragma unroll
      for (int dg = 0; dg < 2; ++dg)
#pragma unroll
        for (int hk = 0; hk < 2; ++hk) {
          bf16x8 va = *(const bf16x8*)
              &VsC[(dg * 32 + l31) * 128 + (((kgi * 2 + hk) * 16 + bh8) ^ vrsw)];
          o_acc[dg][0] = MFMA32(va, pa[0][hk], o_acc[dg][0]);
          o_acc[dg][1] = MFMA32(va, pa[1][hk], o_acc[dg][1]);
        }
      __builtin_amdgcn_s_setprio(0);
    }
    __syncthreads();   // drains staged DMA (vmcnt) + all waves done with KsC/VsC
  }

  // ---- epilogue: normalize, store y_pc [n][p=q][c = h*64 + d] ----
#pragma unroll
  for (int qg = 0; qg < 2; ++qg) {
    float la = l_acc[qg];
    la += __shfl_xor(la, 32);
    float linv = 1.0f / la;
    const int q = q0 + wv * 64 + qg * 32 + l31;
    unsigned short* yb = y_pc + ((long)n * 1024 + q) * 512 + h * 64;
#pragma unroll
    for (int dg = 0; dg < 2; ++dg) {
      f32x16 o = o_acc[dg][qg];
#pragma unroll
      for (int rq = 0; rq < 4; ++rq) {
        int d0 = dg * 32 + rq * 8 + (bh8 >> 1);   // (lane>>5)*4
        ushort4 st;
        st.x = f2bf(o[rq * 4 + 0] * linv);
        st.y = f2bf(o[rq * 4 + 1] * linv);
        st.z = f2bf(o[rq * 4 + 2] * linv);
        st.w = f2bf(o[rq * 4 + 3] * linv);
        *(ushort4*)&yb[d0] = st;
      }
    }
  }
}

// ---------------------------------------------------------------------------
extern "C" void kernel_launch(void* const* d_in, const int* in_sizes, int n_in,
                              void* d_out, int out_size, void* d_ws, size_t ws_size,
                              hipStream_t stream) {
  (void)in_sizes; (void)n_in; (void)out_size; (void)ws_size;
  const float* x     = (const float*)d_in[0];
  const float* qkv_w = (const float*)d_in[1];
  const float* qkv_b = (const float*)d_in[2];
  const float* out_w = (const float*)d_in[3];
  const float* out_b = (const float*)d_in[4];
  const int* de = (const int*)d_in[5];
  float* out = (float*)d_out;
  unsigned short* ws = (unsigned short*)d_ws;

  // ws layout (shorts), ~66 MiB total:
  //   [0, 8388608)            xT, reused as y_pc
  //   [8388608, 33554432)     qkv: q_pd | k_pd | v_cp (8388608 each)
  //   [33554432, 34340864)    wq bf16 (786432)
  //   [34340864, 34603008)    wo bf16 (262144)
  unsigned short* xT   = ws;
  unsigned short* qkv  = ws + 8388608;
  unsigned short* y_pc = ws;
  unsigned short* wq   = ws + 33554432;
  unsigned short* wo   = wq + 786432;

  cvt_bf16<<<3072, 256, 0, stream>>>(qkv_w, wq, 786432);
  cvt_bf16<<<1024, 256, 0, stream>>>(out_w, wo, 262144);

  transpose_cvt<<<dim3(32, 16, 16), 256, 0, stream>>>(x, xT);

  gemm_qkv<<<dim3(12, 8, 16), 256, 0, stream>>>(xT, wq, qkv, qkv_b);

  attn_kernel<<<dim3(4, 128), 256, 0, stream>>>(
      qkv, qkv + 8388608, qkv + 16777216, y_pc);

  gemm_out<<<dim3(4, 8, 16), 256, 0, stream>>>(
      y_pc, wo, out, out_b, x, de);
}

// Round 4
// 186.040 us; speedup vs baseline: 1.2573x; 1.0280x over previous
//
#include <hip/hip_runtime.h>

typedef short bf16x8 __attribute__((ext_vector_type(8)));
typedef float f32x4 __attribute__((ext_vector_type(4)));
typedef float f32x16 __attribute__((ext_vector_type(16)));

#define MFMA16(a,b,c) __builtin_amdgcn_mfma_f32_16x16x32_bf16((a),(b),(c),0,0,0)
#define MFMA32(a,b,c) __builtin_amdgcn_mfma_f32_32x32x16_bf16((a),(b),(c),0,0,0)

static __device__ __forceinline__ unsigned short f2bf(float f){
  unsigned u; __builtin_memcpy(&u, &f, 4);
  u += 0x7fffu + ((u >> 16) & 1u);
  return (unsigned short)(u >> 16);
}

// v_cvt_pk_bf16_f32: D = {lo: bf16(lo), hi: bf16(hi)}  (no builtin on gfx950)
static __device__ __forceinline__ unsigned cvtpk(float lo, float hi){
  unsigned r;
  asm volatile("v_cvt_pk_bf16_f32 %0, %1, %2" : "=v"(r) : "v"(lo), "v"(hi));
  return r;
}
// v_permlane32_swap_b32 a, b:  a[l<32]=b_old[l+32]; b[l>=32]=a_old[l-32]
static __device__ __forceinline__ void pl32swap(unsigned &a, unsigned &b){
  asm volatile("v_permlane32_swap_b32 %0, %1" : "+v"(a), "+v"(b));
}

// async global->LDS DMA, 16 B per lane; LDS dest = wave-uniform base + lane*16
static __device__ __forceinline__ void gload_lds16(const void* g, void* l) {
  __builtin_amdgcn_global_load_lds(
      (__attribute__((address_space(1))) void*)g,
      (__attribute__((address_space(3))) void*)l, 16, 0, 0);
}

// ---------------------------------------------------------------------------
// Stage f32 tensor -> bf16.
// ---------------------------------------------------------------------------
__global__ __launch_bounds__(256) void cvt_bf16(
    const float* __restrict__ in, unsigned short* __restrict__ out, int n) {
  int i = blockIdx.x * 256 + threadIdx.x;
  if (i < n) out[i] = f2bf(in[i]);
}

// ---------------------------------------------------------------------------
// T0: x [n][512 c][1024 p] f32 -> xT [n][1024 p][512 c] bf16
// ---------------------------------------------------------------------------
__global__ __launch_bounds__(256) void transpose_cvt(
    const float* __restrict__ in, unsigned short* __restrict__ out)
{
  __shared__ unsigned short tile[32][33];
  const long base = (long)blockIdx.z * 512 * 1024;
  const int t = threadIdx.x, tx = t & 31, ty = t >> 5;
  const int c0 = blockIdx.x * 32, r0 = blockIdx.y * 32;
  const float* ib = in + base;
#pragma unroll
  for (int i = 0; i < 4; ++i)
    tile[ty + i * 8][tx] = f2bf(ib[(long)(r0 + ty + i * 8) * 1024 + c0 + tx]);
  __syncthreads();
  unsigned short* ob = out + base;
#pragma unroll
  for (int i = 0; i < 4; ++i)
    ob[(long)(c0 + ty + i * 8) * 512 + r0 + tx] = tile[tx][ty + i * 8];
}

// ---------------------------------------------------------------------------
// K1: QKV GEMM. T3-minimal pipeline: double-buffered LDS, stage(next) issued
// BEFORE compute(cur), ONE barrier per K-step (drains the prefetch that had
// the whole MFMA phase to fly). XCD-grouped remap (each XCD = 2 batches).
// Epilogue for q/k routes through a [128][136] LDS transpose tile so global
// writes are 16B-contiguous (was: 2B scalars at 128B stride, 1.7x write amp).
// ---------------------------------------------------------------------------
__global__ __launch_bounds__(256, 2) void gemm_qkv(
    const unsigned short* __restrict__ A, const unsigned short* __restrict__ B,
    unsigned short* __restrict__ qkvout, const float* __restrict__ bias)
{
  const int M = 1024, K = 512;
  __shared__ unsigned short SM[4][128 * 64];   // A0 A1 B0 B1, 64 KB
  const int t = threadIdx.x, lane = t & 63, wv = t >> 6;
  const int quad = lane >> 4, ln = lane & 15;

  // bijective XCD remap: L in [0,1536), v = (L%8)*192 + L/8
  const int L = blockIdx.x + 12 * blockIdx.y + 96 * blockIdx.z;
  const int v = (L & 7) * 192 + (L >> 3);
  const int m0 = ((v / 12) & 7) * 128, n0 = (v % 12) * 128;
  const long zb = v / 96;
  A += zb * (long)M * K;

  const int srow = wv * 32 + (lane >> 3);
  const int scol = ((lane & 7) * 8) ^ ((lane >> 3) * 8);

  auto stage = [&](int kt, unsigned short* Ad, unsigned short* Bd) {
#pragma unroll
    for (int i = 0; i < 4; ++i) {
      gload_lds16(&A[(long)(m0 + srow + i * 8) * K + kt + scol],
                  &Ad[(wv * 32 + i * 8) * 64]);
      gload_lds16(&B[(long)(n0 + srow + i * 8) * K + kt + scol],
                  &Bd[(wv * 32 + i * 8) * 64]);
    }
  };

  f32x4 zero = {0.f, 0.f, 0.f, 0.f};
  f32x4 acc[4][4];
#pragma unroll
  for (int i = 0; i < 4; ++i)
#pragma unroll
    for (int j = 0; j < 4; ++j) acc[i][j] = zero;

  const int wm = (wv & 1) * 64, wn = (wv >> 1) * 64;
  const int rsw = (ln & 7) * 8;

  stage(0, SM[0], SM[2]);
  __syncthreads();
  for (int kt8 = 0; kt8 < 8; ++kt8) {
    const int cur = kt8 & 1;
    if (kt8 < 7) stage((kt8 + 1) * 64, SM[cur ^ 1], SM[2 + (cur ^ 1)]);
    const unsigned short* As = SM[cur];
    const unsigned short* Bs = SM[2 + cur];
#pragma unroll
    for (int kk = 0; kk < 64; kk += 32) {
      bf16x8 a[4], b[4];
#pragma unroll
      for (int i = 0; i < 4; ++i)
        a[i] = *(const bf16x8*)&As[(wm + i * 16 + ln) * 64 + ((kk + quad * 8) ^ rsw)];
#pragma unroll
      for (int j = 0; j < 4; ++j)
        b[j] = *(const bf16x8*)&Bs[(wn + j * 16 + ln) * 64 + ((kk + quad * 8) ^ rsw)];
#pragma unroll
      for (int i = 0; i < 4; ++i)
#pragma unroll
        for (int j = 0; j < 4; ++j)
          acc[i][j] = MFMA16(a[i], b[j], acc[i][j]);
    }
    __syncthreads();   // prefetch landed + all waves done with cur buffers
  }

  const int part = n0 >> 9;   // uniform per block: 0=q, 1=k, 2=v
  if (part < 2) {
    // ---- transpose epilogue through LDS: T[p][o'] bf16, padded row 136 ----
    const float qs = (part == 0) ? 0.18033688f : 1.0f;  // 0.125 * log2(e)
    unsigned short (*T)[136] = (unsigned short(*)[136])&SM[0][0];  // 34 KB
#pragma unroll
    for (int j = 0; j < 4; ++j) {
      const int oo = wn + j * 16 + ln;
      const float bb = bias[n0 + oo];
#pragma unroll
      for (int i = 0; i < 4; ++i) {
        const int pp = wm + i * 16 + quad * 4;
        f32x4 vv = acc[i][j];
#pragma unroll
        for (int r = 0; r < 4; ++r)
          T[pp + r][oo] = f2bf((vv[r] + bb) * qs);
      }
    }
    __syncthreads();
    unsigned short* qb = qkvout + (long)part * 8388608;
#pragma unroll
    for (int it = 0; it < 8; ++it) {
      const int idx = it * 256 + t;
      const int p = idx >> 4, c0 = (idx & 15) * 8;
      const int og = n0 + c0;
      const int h = (og >> 6) & 7, d = og & 63;
      bf16x8 val = *(const bf16x8*)&T[p][c0];
      *(bf16x8*)&qb[((long)(zb * 8 + h) * 1024 + m0 + p) * 64 + d] = val;
    }
  } else {
    // ---- v part: [c][p] layout, stores already p-contiguous ----
#pragma unroll
    for (int j = 0; j < 4; ++j) {
      const int o = n0 + wn + j * 16 + ln;
      const float bb = bias[o];
#pragma unroll
      for (int i = 0; i < 4; ++i) {
        const int p = m0 + wm + i * 16 + quad * 4;
        const long cidx = ((long)zb * 512 + (o - 1024)) * 1024 + p;
        f32x4 vv = acc[i][j];
        ushort4 st;
        st.x = f2bf(vv[0] + bb); st.y = f2bf(vv[1] + bb);
        st.z = f2bf(vv[2] + bb); st.w = f2bf(vv[3] + bb);
        *(ushort4*)&qkvout[16777216 + cidx] = st;
      }
    }
  }
}

// ---------------------------------------------------------------------------
// K3: OUT GEMM, same T3-minimal pipeline + XCD remap; bias+dropout+residual.
// ---------------------------------------------------------------------------
__global__ __launch_bounds__(256, 2) void gemm_out(
    const unsigned short* __restrict__ A, const unsigned short* __restrict__ B,
    float* __restrict__ C, const float* __restrict__ bias,
    const float* __restrict__ xin, const int* __restrict__ de_ptr)
{
  const int M = 1024, K = 512;
  __shared__ unsigned short SM[4][128 * 64];   // A0 A1 B0 B1, 64 KB
  const int t = threadIdx.x, lane = t & 63, wv = t >> 6;
  const int quad = lane >> 4, ln = lane & 15;

  // bijective XCD remap: L in [0,512), v = (L%8)*64 + L/8
  const int L = blockIdx.x + 4 * blockIdx.y + 32 * blockIdx.z;
  const int v = (L & 7) * 64 + (L >> 3);
  const int m0 = ((v >> 2) & 7) * 128, n0 = (v & 3) * 128;
  const long zb = v >> 5;
  A += zb * (long)M * K;
  C += zb * 512l * M;
  xin += zb * 512l * M;

  const int srow = wv * 32 + (lane >> 3);
  const int scol = ((lane & 7) * 8) ^ ((lane >> 3) * 8);

  auto stage = [&](int kt, unsigned short* Ad, unsigned short* Bd) {
#pragma unroll
    for (int i = 0; i < 4; ++i) {
      gload_lds16(&A[(long)(m0 + srow + i * 8) * K + kt + scol],
                  &Ad[(wv * 32 + i * 8) * 64]);
      gload_lds16(&B[(long)(n0 + srow + i * 8) * K + kt + scol],
                  &Bd[(wv * 32 + i * 8) * 64]);
    }
  };

  f32x4 zero = {0.f, 0.f, 0.f, 0.f};
  f32x4 acc[4][4];
#pragma unroll
  for (int i = 0; i < 4; ++i)
#pragma unroll
    for (int j = 0; j < 4; ++j) acc[i][j] = zero;

  const int wm = (wv & 1) * 64, wn = (wv >> 1) * 64;
  const int rsw = (ln & 7) * 8;

  stage(0, SM[0], SM[2]);
  __syncthreads();
  for (int kt8 = 0; kt8 < 8; ++kt8) {
    const int cur = kt8 & 1;
    if (kt8 < 7) stage((kt8 + 1) * 64, SM[cur ^ 1], SM[2 + (cur ^ 1)]);
    const unsigned short* As = SM[cur];
    const unsigned short* Bs = SM[2 + cur];
#pragma unroll
    for (int kk = 0; kk < 64; kk += 32) {
      bf16x8 a[4], b[4];
#pragma unroll
      for (int i = 0; i < 4; ++i)
        a[i] = *(const bf16x8*)&As[(wm + i * 16 + ln) * 64 + ((kk + quad * 8) ^ rsw)];
#pragma unroll
      for (int j = 0; j < 4; ++j)
        b[j] = *(const bf16x8*)&Bs[(wn + j * 16 + ln) * 64 + ((kk + quad * 8) ^ rsw)];
#pragma unroll
      for (int i = 0; i < 4; ++i)
#pragma unroll
        for (int j = 0; j < 4; ++j)
          acc[i][j] = MFMA16(a[i], b[j], acc[i][j]);
    }
    __syncthreads();
  }

  float dscale = 1.0f / (1.0f - 0.1f * (float)de_ptr[0]);

#pragma unroll
  for (int j = 0; j < 4; ++j) {
    int o = n0 + wn + j * 16 + ln;
    float bb = bias[o];
#pragma unroll
    for (int i = 0; i < 4; ++i) {
      int p = m0 + wm + i * 16 + quad * 4;
      long cidx = (long)o * M + p;
      f32x4 vv = acc[i][j];
      float4 rx = *(const float4*)&xin[cidx];
      float4 st;
      st.x = rx.x + (vv[0] + bb) * dscale;
      st.y = rx.y + (vv[1] + bb) * dscale;
      st.z = rx.z + (vv[2] + bb) * dscale;
      st.w = rx.w + (vv[3] + bb) * dscale;
      *(float4*)&C[cidx] = st;
    }
  }
}

// ---------------------------------------------------------------------------
// Flash attention v8: 32x32x16 MFMA, 256 q/block, in-register P via
// cvt_pk+permlane32_swap, double-buffered K/V DMA, XCD-grouping swizzle,
// wide Vs swizzle (chunk ^= row&15), s_setprio around MFMA clusters.
// ---------------------------------------------------------------------------
__global__ __launch_bounds__(256, 2) void attn_kernel(
    const unsigned short* __restrict__ q_pd, const unsigned short* __restrict__ k_pd,
    const unsigned short* __restrict__ v_cp, unsigned short* __restrict__ y_pc)
{
  __shared__ unsigned short Ks[2][128 * 64];     // 2 x 16 KB, DMA dest
  __shared__ unsigned short Vs[2][64 * 128];     // 2 x 16 KB, DMA dest
  const int t = threadIdx.x, lane = t & 63, wv = t >> 6;
  const int l31 = lane & 31, bh8 = (lane >> 5) * 8;
  const int qt = blockIdx.y >> 5;                     // 0..3 q-tile
  const int nh = blockIdx.x * 32 + (blockIdx.y & 31); // 0..127
  const int n = nh >> 3, h = nh & 7;
  const int q0 = qt * 256;

  // Q fragments (B-operand, 32x32x16): n=q=l31, k=d=ds*16+bh8+j. Pre-scaled.
  bf16x8 qa[2][4];
#pragma unroll
  for (int qg = 0; qg < 2; ++qg) {
    const unsigned short* qb =
        q_pd + ((long)nh * 1024 + q0 + wv * 64 + qg * 32 + l31) * 64;
#pragma unroll
    for (int ds = 0; ds < 4; ++ds)
      qa[qg][ds] = *(const bf16x8*)(qb + ds * 16 + bh8);
  }

  f32x16 zacc;
#pragma unroll
  for (int r = 0; r < 16; ++r) zacc[r] = 0.f;
  f32x16 o_acc[2][2];
  o_acc[0][0] = zacc; o_acc[0][1] = zacc; o_acc[1][0] = zacc; o_acc[1][1] = zacc;
  float l_acc[2] = {0.f, 0.f};

  const unsigned short* kg0 = k_pd + (long)nh * 1024 * 64;
  const unsigned short* vg0 = v_cp + ((long)n * 512 + h * 64) * 1024;

  const int krow = lane >> 3;
  const int kcol = ((lane & 7) * 8) ^ ((lane >> 3) * 8);
  const int vrow = lane >> 4;
  const int rsw = (lane & 7) * 8;     // K read XOR (frag row&7 == lane&7)
  const int vrsw = (l31 & 15) * 8;    // V read XOR (frag row&15 == l31&15)

  // prologue: stage chunk 0 into buffer 0
#pragma unroll
  for (int i = 0; i < 4; ++i) {
    const int vr = i * 4 + vrow;                        // row & 15
    const int vcol = ((lane & 15) ^ vr) * 8;
    gload_lds16(kg0 + (long)(wv * 32 + i * 8 + krow) * 64 + kcol,
                &Ks[0][(wv * 32 + i * 8) * 64]);
    gload_lds16(vg0 + (long)(wv * 16 + vr) * 1024 + vcol,
                &Vs[0][(wv * 16 + i * 4) * 128]);
  }
  __syncthreads();

  union U { bf16x8 v; unsigned u[4]; };
  auto sm_pack = [&](const f32x16& sv, bf16x8* paq, float& lac) {
    float e[16];
#pragma unroll
    for (int r = 0; r < 16; ++r) e[r] = __builtin_amdgcn_exp2f(sv[r]);
    float ls = 0.f;
#pragma unroll
    for (int r = 0; r < 16; ++r) ls += e[r];
    lac += ls;
    unsigned pk4[4][2];
#pragma unroll
    for (int hh = 0; hh < 4; ++hh) {
      pk4[hh][0] = cvtpk(e[4 * hh + 0], e[4 * hh + 1]);
      pk4[hh][1] = cvtpk(e[4 * hh + 2], e[4 * hh + 3]);
    }
#pragma unroll
    for (int hk = 0; hk < 2; ++hk) {
      unsigned a0 = pk4[2 * hk + 1][0], b0 = pk4[2 * hk][0];
      unsigned a1 = pk4[2 * hk + 1][1], b1 = pk4[2 * hk][1];
      pl32swap(a0, b0); pl32swap(a1, b1);
      U u; u.u[0] = b0; u.u[1] = b1; u.u[2] = a0; u.u[3] = a1;
      paq[hk] = u.v;
    }
  };

  for (int c = 0; c < 8; ++c) {
    const int cur = c & 1;
    if (c < 7) {
      const unsigned short* kg = kg0 + (long)(c + 1) * 128 * 64;
      const unsigned short* vg = vg0 + (c + 1) * 128;
      unsigned short* KsD = Ks[cur ^ 1];
      unsigned short* VsD = Vs[cur ^ 1];
#pragma unroll
      for (int i = 0; i < 4; ++i) {
        const int vr = i * 4 + vrow;
        const int vcol = ((lane & 15) ^ vr) * 8;
        gload_lds16(kg + (long)(wv * 32 + i * 8 + krow) * 64 + kcol,
                    &KsD[(wv * 32 + i * 8) * 64]);
        gload_lds16(vg + (long)(wv * 16 + vr) * 1024 + vcol,
                    &VsD[(wv * 16 + i * 4) * 128]);
      }
    }
    const unsigned short* KsC = Ks[cur];
    const unsigned short* VsC = Vs[cur];

#pragma unroll
    for (int kgi = 0; kgi < 4; ++kgi) {
      f32x16 s0 = zacc, s1 = zacc;
      __builtin_amdgcn_s_setprio(1);
#pragma unroll
      for (int ds = 0; ds < 4; ++ds) {
        bf16x8 ka = *(const bf16x8*)&KsC[(kgi * 32 + l31) * 64 + ((ds * 16 + bh8) ^ rsw)];
        s0 = MFMA32(ka, qa[0][ds], s0);
        s1 = MFMA32(ka, qa[1][ds], s1);
      }
      __builtin_amdgcn_s_setprio(0);
      bf16x8 pa[2][2];
      sm_pack(s0, pa[0], l_acc[0]);
      sm_pack(s1, pa[1], l_acc[1]);
      __builtin_amdgcn_s_setprio(1);
#pragma unroll
      for (int dg = 0; dg < 2; ++dg)
#pragma unroll
        for (int hk = 0; hk < 2; ++hk) {
          bf16x8 va = *(const bf16x8*)
              &VsC[(dg * 32 + l31) * 128 + (((kgi * 2 + hk) * 16 + bh8) ^ vrsw)];
          o_acc[dg][0] = MFMA32(va, pa[0][hk], o_acc[dg][0]);
          o_acc[dg][1] = MFMA32(va, pa[1][hk], o_acc[dg][1]);
        }
      __builtin_amdgcn_s_setprio(0);
    }
    __syncthreads();
  }

#pragma unroll
  for (int qg = 0; qg < 2; ++qg) {
    float la = l_acc[qg];
    la += __shfl_xor(la, 32);
    float linv = 1.0f / la;
    const int q = q0 + wv * 64 + qg * 32 + l31;
    unsigned short* yb = y_pc + ((long)n * 1024 + q) * 512 + h * 64;
#pragma unroll
    for (int dg = 0; dg < 2; ++dg) {
      f32x16 o = o_acc[dg][qg];
#pragma unroll
      for (int rq = 0; rq < 4; ++rq) {
        int d0 = dg * 32 + rq * 8 + (bh8 >> 1);   // (lane>>5)*4
        ushort4 st;
        st.x = f2bf(o[rq * 4 + 0] * linv);
        st.y = f2bf(o[rq * 4 + 1] * linv);
        st.z = f2bf(o[rq * 4 + 2] * linv);
        st.w = f2bf(o[rq * 4 + 3] * linv);
        *(ushort4*)&yb[d0] = st;
      }
    }
  }
}

// ---------------------------------------------------------------------------
extern "C" void kernel_launch(void* const* d_in, const int* in_sizes, int n_in,
                              void* d_out, int out_size, void* d_ws, size_t ws_size,
                              hipStream_t stream) {
  (void)in_sizes; (void)n_in; (void)out_size; (void)ws_size;
  const float* x     = (const float*)d_in[0];
  const float* qkv_w = (const float*)d_in[1];
  const float* qkv_b = (const float*)d_in[2];
  const float* out_w = (const float*)d_in[3];
  const float* out_b = (const float*)d_in[4];
  const int* de = (const int*)d_in[5];
  float* out = (float*)d_out;
  unsigned short* ws = (unsigned short*)d_ws;

  // ws layout (shorts), ~66 MiB total:
  //   [0, 8388608)            xT, reused as y_pc
  //   [8388608, 33554432)     qkv: q_pd | k_pd | v_cp (8388608 each)
  //   [33554432, 34340864)    wq bf16 (786432)
  //   [34340864, 34603008)    wo bf16 (262144)
  unsigned short* xT   = ws;
  unsigned short* qkv  = ws + 8388608;
  unsigned short* y_pc = ws;
  unsigned short* wq   = ws + 33554432;
  unsigned short* wo   = wq + 786432;

  cvt_bf16<<<3072, 256, 0, stream>>>(qkv_w, wq, 786432);
  cvt_bf16<<<1024, 256, 0, stream>>>(out_w, wo, 262144);

  transpose_cvt<<<dim3(32, 16, 16), 256, 0, stream>>>(x, xT);

  gemm_qkv<<<dim3(12, 8, 16), 256, 0, stream>>>(xT, wq, qkv, qkv_b);

  attn_kernel<<<dim3(4, 128), 256, 0, stream>>>(
      qkv, qkv + 8388608, qkv + 16777216, y_pc);

  gemm_out<<<dim3(4, 8, 16), 256, 0, stream>>>(
      y_pc, wo, out, out_b, x, de);
}